// Round 17
// baseline (109.672 us; speedup 1.0000x reference)
//
#include <hip/hip_runtime.h>
#include <hip/hip_bf16.h>
#include <stdint.h>

#define SEQ    2048
#define DM     512
#define NHEAD  8
#define HD     64
#define BATCH  4
#define MTOT   (BATCH*SEQ)   // 8192

typedef __attribute__((ext_vector_type(4))) float  f32x4;
typedef __attribute__((ext_vector_type(8))) short  bf16x8;
typedef __attribute__((ext_vector_type(8))) unsigned short u16x8;
typedef __attribute__((ext_vector_type(4))) unsigned short u16x4;
typedef __attribute__((ext_vector_type(4))) float  fl4;
typedef __attribute__((ext_vector_type(2))) unsigned u32x2;
typedef __attribute__((ext_vector_type(4))) unsigned u32x4;

__device__ __forceinline__ unsigned short f2bf(float f) {
  union { float f; unsigned u; } c; c.f = f;
  return (unsigned short)((c.u + 0x7fffu + ((c.u >> 16) & 1u)) >> 16);
}

__device__ __forceinline__ float bf2f(unsigned short s) {
  unsigned u = (unsigned)s << 16;
  float f; __builtin_memcpy(&f, &u, 4);
  return f;
}

__device__ __forceinline__ void load_lds16(const void* g, void* l) {
  __builtin_amdgcn_global_load_lds((__attribute__((address_space(1))) void*)g,
                                   (__attribute__((address_space(3))) void*)l,
                                   16, 0, 0);
}

// hardware transpose read: 64b per lane, 16-bit element transpose in 16-lane groups
__device__ __forceinline__ u32x2 ds_tr16(const void* p) {
  u32x2 r;
  asm volatile("ds_read_b64_tr_b16 %0, %1"
               : "=v"(r)
               : "v"((__attribute__((address_space(3))) const void*)p));
  return r;
}

// packed f32 pair -> bf16x2 dword (v_cvt_pk_bf16_f32)
__device__ __forceinline__ unsigned pack_bf2(float lo, float hi) {
  __hip_bfloat162 h2 = __float22bfloat162_rn(float2{lo, hi});
  unsigned u; __builtin_memcpy(&u, &h2, 4);
  return u;
}

// ---------------- merged preprocessing: casts + weight transposes -----------
__global__ void k_pre(const float* __restrict__ X, unsigned short* __restrict__ Xb,
                      const float* __restrict__ C, unsigned short* __restrict__ Cb,
                      const float* __restrict__ Wq, unsigned short* __restrict__ Wqt,
                      const float* __restrict__ Wkv, unsigned short* __restrict__ Wkvt,
                      const float* __restrict__ Wo, unsigned short* __restrict__ Wot) {
  __shared__ __align__(16) unsigned short t[64][66];
  int bid = blockIdx.x, tid = threadIdx.x;
  if (bid < 8192) {
    const float* src = (bid < 4096) ? X : C;
    unsigned short* dst = (bid < 4096) ? Xb : Cb;
    int i = (bid & 4095) * 256 + tid;
    fl4 v = *(const fl4*)(src + (size_t)i * 4);
    u32x2 o;
    o[0] = pack_bf2(v[0], v[1]);
    o[1] = pack_bf2(v[2], v[3]);
    *(u32x2*)((void*)(dst + (size_t)i * 4)) = o;
    return;
  }
  int tjob = bid - 8192;
  const float* W; unsigned short* Wt; int Nd, bx, by;
  if (tjob < 64)       { W = Wq;  Wt = Wqt;  Nd = 512;  bx = tjob & 7;  by = tjob >> 3; }
  else if (tjob < 192) { int u = tjob - 64;  W = Wkv; Wt = Wkvt; Nd = 1024; bx = u & 15; by = u >> 4; }
  else                 { int u = tjob - 192; W = Wo;  Wt = Wot;  Nd = 512;  bx = u & 7;  by = u >> 3; }
  int k0 = by * 64, n0 = bx * 64;
  int r = tid >> 2, cs = (tid & 3) * 16;
  const float* src = W + (size_t)(k0 + r) * Nd + n0 + cs;
#pragma unroll
  for (int i = 0; i < 4; ++i) {
    fl4 v = *(const fl4*)(src + i * 4);
    *(unsigned*)&t[r][cs + i*4]     = pack_bf2(v[0], v[1]);
    *(unsigned*)&t[r][cs + i*4 + 2] = pack_bf2(v[2], v[3]);
  }
  __syncthreads();
  unsigned short* drow = Wt + (size_t)(n0 + r) * 512 + k0 + cs;
#pragma unroll
  for (int half = 0; half < 2; ++half) {
    u16x8 o;
#pragma unroll
    for (int i = 0; i < 8; ++i) o[i] = t[cs + half*8 + i][r];
    *(u16x8*)(drow + half * 8) = o;
  }
}

// ------ 128x64-tile GEMM, 2-phase prefetch double-buffered ------------------
template<int RESID>
__device__ __forceinline__ void gemm128x64(
    const unsigned short* __restrict__ A,
    const unsigned short* __restrict__ Bt,
    const float* __restrict__ bias,
    const unsigned short* __restrict__ res,
    unsigned short* __restrict__ Cout,
    int N, int K, int m0, int n0, float osc,
    unsigned short* Als, unsigned short* Bls) {
  int tid  = threadIdx.x;
  int lane = tid & 63, wave = tid >> 6;
  int q = lane & 15, lk = lane >> 4;
  f32x4 acc[2][4];
#pragma unroll
  for (int mt = 0; mt < 2; ++mt)
#pragma unroll
    for (int nt = 0; nt < 4; ++nt) acc[mt][nt] = f32x4{0.f,0.f,0.f,0.f};

  const unsigned short* gA[4];
#pragma unroll
  for (int it = 0; it < 4; ++it) {
    int idx = tid + it * 256;
    int row = idx >> 3, ch = idx & 7, sc = ch ^ (row & 7);
    gA[it] = A + (size_t)(m0 + row) * K + sc * 8;
  }
  const unsigned short* gB[2];
#pragma unroll
  for (int it = 0; it < 2; ++it) {
    int idx = tid + it * 256;
    int row = idx >> 3, ch = idx & 7, sc = ch ^ (row & 7);
    gB[it] = Bt + (size_t)(n0 + row) * K + sc * 8;
  }
  char* aD = (char*)Als + tid * 16;
  char* bD = (char*)Bls + tid * 16;

#pragma unroll
  for (int it = 0; it < 4; ++it) { load_lds16(gA[it], aD + it * 4096); gA[it] += 64; }
#pragma unroll
  for (int it = 0; it < 2; ++it) { load_lds16(gB[it], bD + it * 4096); gB[it] += 64; }
  __syncthreads();

  int nkb = K >> 6;
  int buf = 0;
  for (int kb = 0; kb < nkb; ++kb) {
    if (kb + 1 < nkb) {
      char* aN = aD + (buf ^ 1) * 16384;
      char* bN = bD + (buf ^ 1) * 8192;
#pragma unroll
      for (int it = 0; it < 4; ++it) { load_lds16(gA[it], aN + it * 4096); gA[it] += 64; }
#pragma unroll
      for (int it = 0; it < 2; ++it) { load_lds16(gB[it], bN + it * 4096); gB[it] += 64; }
    }
    const char* aR = (const char*)Als + buf * 16384;
    const char* bR = (const char*)Bls + buf * 8192;
#pragma unroll
    for (int ks = 0; ks < 2; ++ks) {
      bf16x8 a[2], b[4];
#pragma unroll
      for (int mt = 0; mt < 2; ++mt) {
        int row = wave * 32 + mt * 16 + q;
        a[mt] = *(const bf16x8*)(aR + row * 128 + (((ks*4 + lk) ^ (row & 7)) * 16));
      }
#pragma unroll
      for (int nt = 0; nt < 4; ++nt) {
        int row = nt * 16 + q;
        b[nt] = *(const bf16x8*)(bR + row * 128 + (((ks*4 + lk) ^ (row & 7)) * 16));
      }
#pragma unroll
      for (int mt = 0; mt < 2; ++mt)
#pragma unroll
        for (int nt = 0; nt < 4; ++nt)
          acc[mt][nt] = __builtin_amdgcn_mfma_f32_16x16x32_bf16(a[mt], b[nt], acc[mt][nt], 0, 0, 0);
    }
    __syncthreads();
    buf ^= 1;
  }
#pragma unroll
  for (int nt = 0; nt < 4; ++nt) {
    int col = n0 + nt * 16 + q;
    float bv = bias[col];
#pragma unroll
    for (int mt = 0; mt < 2; ++mt) {
      int rowb = m0 + wave * 32 + mt * 16 + lk * 4;
#pragma unroll
      for (int rr = 0; rr < 4; ++rr) {
        float v = acc[mt][nt][rr] + bv;
        size_t off = (size_t)(rowb + rr) * N + col;
        if (RESID) Cout[off] = f2bf(v + bf2f(res[off]));
        else       Cout[off] = f2bf(v * osc);
      }
    }
  }
}

// merged Q-proj + KV-proj. grid 1536 (XCD-swizzled): l<512 -> Q, else KV.
__global__ __launch_bounds__(256, 3)
void k_projmm(const unsigned short* __restrict__ Xb, const unsigned short* __restrict__ Cb,
              const unsigned short* __restrict__ Wqt, const unsigned short* __restrict__ Wkvt,
              const float* __restrict__ bq, const float* __restrict__ bkv,
              unsigned short* __restrict__ Qb, unsigned short* __restrict__ KVb) {
  __shared__ __align__(16) unsigned short Als[2 * 128 * 64];
  __shared__ __align__(16) unsigned short Bls[2 * 64 * 64];
  int bid = blockIdx.x;
  int l = (bid & 7) * 192 + (bid >> 3);
  const float c1 = 0.125f * 1.44269504088896340736f;
  if (l < 512) {
    int m = l >> 3, n = l & 7;
    gemm128x64<0>(Xb, Wqt, bq, nullptr, Qb, 512, 512, m * 128, n * 64, c1, Als, Bls);
  } else {
    int l2 = l - 512;
    int m = l2 >> 4, n = l2 & 15;
    gemm128x64<0>(Cb, Wkvt, bkv, nullptr, KVb, 1024, 512, m * 128, n * 64, 1.0f, Als, Bls);
  }
}

// O-proj + bias + bf16 residual -> bf16 tmp. grid 512 (XCD-swizzled).
__global__ __launch_bounds__(256, 3)
void k_omm(const unsigned short* __restrict__ Abuf, const unsigned short* __restrict__ Wot,
           const float* __restrict__ bo, const unsigned short* __restrict__ residb,
           unsigned short* __restrict__ tmp) {
  __shared__ __align__(16) unsigned short Als[2 * 128 * 64];
  __shared__ __align__(16) unsigned short Bls[2 * 64 * 64];
  int bid = blockIdx.x;
  int l = (bid & 7) * 64 + (bid >> 3);
  int m = l >> 3, n = l & 7;
  gemm128x64<1>(Abuf, Wot, bo, residb, tmp, 512, 512, m * 128, n * 64, 1.0f, Als, Bls);
}

// ---------------- flash attention v15: counted-vmcnt pipeline ----------------
// Depth-2 staging: body kb issues V(kb+1) then K(kb+2); ends with
// s_waitcnt vmcnt(4) (drains the PREVIOUS body's loads, leaves this body's 4
// in flight across the barrier) + raw s_barrier — no vmcnt(0) drain in the
// main loop (T4). K and V both in 3 buffers (tile t -> buf t%3), period-3
// static unroll. 48 KB LDS. No-max softmax; permlane P-network; tr16 V reads.
__global__ __launch_bounds__(256, 3)
void k_attn(const unsigned short* __restrict__ Qb,
            const unsigned short* __restrict__ KVb,
            unsigned short* __restrict__ Ab) {
  __shared__ __align__(16) unsigned short Klds[3][4096];
  __shared__ __align__(16) unsigned short Vlds[3][4096];
  int tid  = threadIdx.x;
  int lane = tid & 63;
  int q    = lane & 15, lk = lane >> 4;
  int bid = blockIdx.x;
  int swz = (bid & 7) * 128 + (bid >> 3);   // 128 blocks (4 bh) per XCD
  int qt = swz & 31, bh = swz >> 5;
  int b  = bh >> 3, h = bh & 7;
  int q0 = qt * 64 + (tid >> 6) * 16;
  const size_t kvbase = (size_t)b * SEQ * 1024;

  // Q fragments (16 rows per wave)
  bf16x8 qf0, qf1;
  {
    size_t qrow = (size_t)b * SEQ + q0 + q;
    qf0 = *(const bf16x8*)(Qb + qrow * DM + h * HD + lk * 8);
    qf1 = *(const bf16x8*)(Qb + qrow * DM + h * HD + 32 + lk * 8);
  }
  f32x4 acc[4];
#pragma unroll
  for (int i = 0; i < 4; ++i) acc[i] = f32x4{0.f,0.f,0.f,0.f};
  float l = 0.f;            // per-lane partial row-sum (reduced at the end)
  u32x4 pbA[2];

  // ---- strength-reduced staging pointers (advance += 65536 per tile) ----
  const unsigned short *gK0, *gK1, *gV0, *gV1;
  {
    int r0 = tid >> 3, s0_ = (tid & 7) ^ (r0 & 7);
    gK0 = KVb + kvbase + (size_t)r0 * 1024 + h * HD + s0_ * 8;
    int i1 = tid + 256, r1 = i1 >> 3, s1_ = (i1 & 7) ^ (r1 & 7);
    gK1 = KVb + kvbase + (size_t)r1 * 1024 + h * HD + s1_ * 8;
    int dt0 = tid >> 7, w0 = tid & 127, p0 = w0 >> 1, c80 = (w0 & 1) * 8;
    int t0 = (p0 & 32) + (((p0 >> 2) & 3) << 3) + (((p0 >> 4) & 1) << 2) + (p0 & 3);
    gV0 = KVb + kvbase + (size_t)t0 * 1024 + 512 + h * HD + dt0 * 16 + c80;
    int i1v = tid + 256, dt1 = i1v >> 7, w1 = i1v & 127, p1 = w1 >> 1, c81 = (w1 & 1) * 8;
    int t1 = (p1 & 32) + (((p1 >> 2) & 3) << 3) + (((p1 >> 4) & 1) << 2) + (p1 & 3);
    gV1 = KVb + kvbase + (size_t)t1 * 1024 + 512 + h * HD + dt1 * 16 + c81;
  }
  char* kw0 = (char*)Klds[0] + tid * 16;
  char* kw1 = (char*)Klds[1] + tid * 16;
  char* kw2 = (char*)Klds[2] + tid * 16;
  char* vw0 = (char*)Vlds[0] + tid * 16;
  char* vw1 = (char*)Vlds[1] + tid * 16;
  char* vw2 = (char*)Vlds[2] + tid * 16;
  const char* kr0 = (const char*)Klds[0];
  const char* kr1 = (const char*)Klds[1];
  const char* kr2 = (const char*)Klds[2];
  const char* vr0 = (const char*)Vlds[0] + lane * 8;
  const char* vr1 = (const char*)Vlds[1] + lane * 8;
  const char* vr2 = (const char*)Vlds[2] + lane * 8;

#define STAGE_VT(vd_) do {                          \
    load_lds16(gV0, (vd_));                         \
    load_lds16(gV1, (vd_) + 4096);                  \
    gV0 += 65536; gV1 += 65536;                     \
  } while (0)
#define STAGE_KT(kd_) do {                          \
    load_lds16(gK0, (kd_));                         \
    load_lds16(gK1, (kd_) + 4096);                  \
    gK0 += 65536; gK1 += 65536;                     \
  } while (0)
#define VMCNT_BARRIER(N) do {                                        \
    asm volatile("s_waitcnt vmcnt(" #N ")" ::: "memory");            \
    __builtin_amdgcn_sched_barrier(0);                               \
    __builtin_amdgcn_s_barrier();                                    \
  } while (0)

// one tile body. SV/SK literal 0/1; WAITN literal vmcnt target at body end.
#define ABODY(DO_PV, SV, SK, WAITN, kdst_, vdst_, krd_, vprd_) do {          \
    if (SV) STAGE_VT(vdst_);                                                 \
    if (SK) STAGE_KT(kdst_);                                                 \
    if (DO_PV) {                                                             \
      u32x2 tr[2][4][2];                                                     \
      _Pragma("unroll")                                                      \
      for (int ks2 = 0; ks2 < 2; ++ks2)                                      \
        _Pragma("unroll")                                                    \
        for (int dt = 0; dt < 4; ++dt)                                       \
          _Pragma("unroll")                                                  \
          for (int u = 0; u < 2; ++u)                                        \
            tr[ks2][dt][u] = ds_tr16((vprd_) + dt * 2048 + ks2 * 1024 + u * 512); \
      asm volatile("s_waitcnt lgkmcnt(8)" ::: "memory");                     \
      __builtin_amdgcn_sched_barrier(0);                                     \
      __builtin_amdgcn_s_setprio(1);                                         \
      {                                                                      \
        union { u32x4 u; bf16x8 v; } pb;                                     \
        pb.u = pbA[0];                                                       \
        _Pragma("unroll")                                                    \
        for (int dt = 0; dt < 4; ++dt) {                                     \
          union { u32x4 u; bf16x8 v; } cv;                                   \
          cv.u[0] = tr[0][dt][0][0]; cv.u[1] = tr[0][dt][0][1];              \
          cv.u[2] = tr[0][dt][1][0]; cv.u[3] = tr[0][dt][1][1];              \
          acc[dt] = __builtin_amdgcn_mfma_f32_16x16x32_bf16(cv.v, pb.v, acc[dt], 0, 0, 0); \
        }                                                                    \
      }                                                                      \
      asm volatile("s_waitcnt lgkmcnt(0)" ::: "memory");                     \
      __builtin_amdgcn_sched_barrier(0);                                     \
      {                                                                      \
        union { u32x4 u; bf16x8 v; } pb;                                     \
        pb.u = pbA[1];                                                       \
        _Pragma("unroll")                                                    \
        for (int dt = 0; dt < 4; ++dt) {                                     \
          union { u32x4 u; bf16x8 v; } cv;                                   \
          cv.u[0] = tr[1][dt][0][0]; cv.u[1] = tr[1][dt][0][1];              \
          cv.u[2] = tr[1][dt][1][0]; cv.u[3] = tr[1][dt][1][1];              \
          acc[dt] = __builtin_amdgcn_mfma_f32_16x16x32_bf16(cv.v, pb.v, acc[dt], 0, 0, 0); \
        }                                                                    \
      }                                                                      \
      __builtin_amdgcn_s_setprio(0);                                         \
    }                                                                        \
    f32x4 st[4];                                                             \
    _Pragma("unroll")                                                        \
    for (int kt = 0; kt < 4; ++kt) st[kt] = f32x4{0.f,0.f,0.f,0.f};          \
    __builtin_amdgcn_s_setprio(1);                                           \
    _Pragma("unroll")                                                        \
    for (int kt = 0; kt < 4; ++kt) {                                         \
      int row = kt * 16 + q;                                                 \
      bf16x8 kf0 = *(const bf16x8*)((krd_) + row * 128 + ((lk ^ (row & 7)) * 16)); \
      bf16x8 kf1 = *(const bf16x8*)((krd_) + row * 128 + (((4 + lk) ^ (row & 7)) * 16)); \
      st[kt] = __builtin_amdgcn_mfma_f32_16x16x32_bf16(kf0, qf0, st[kt], 0, 0, 0); \
      st[kt] = __builtin_amdgcn_mfma_f32_16x16x32_bf16(kf1, qf1, st[kt], 0, 0, 0); \
    }                                                                        \
    __builtin_amdgcn_s_setprio(0);                                           \
    float p[4][4];                                                           \
    _Pragma("unroll")                                                        \
    for (int kt = 0; kt < 4; ++kt)                                           \
      _Pragma("unroll")                                                      \
      for (int r = 0; r < 4; ++r) {                                          \
        float pe = __builtin_amdgcn_exp2f(st[kt][r]);                        \
        p[kt][r] = pe;                                                       \
        l += pe;                                                             \
      }                                                                      \
    _Pragma("unroll")                                                        \
    for (int ks2 = 0; ks2 < 2; ++ks2) {                                      \
      unsigned u0 = pack_bf2(p[2*ks2][0],     p[2*ks2][1]);                  \
      unsigned u1 = pack_bf2(p[2*ks2][2],     p[2*ks2][3]);                  \
      unsigned u2 = pack_bf2(p[2*ks2 + 1][0], p[2*ks2 + 1][1]);              \
      unsigned u3 = pack_bf2(p[2*ks2 + 1][2], p[2*ks2 + 1][3]);              \
      asm("v_permlane32_swap_b32 %0, %1" : "+v"(u0), "+v"(u2));              \
      asm("v_permlane32_swap_b32 %0, %1" : "+v"(u1), "+v"(u3));              \
      asm("v_permlane16_swap_b32 %0, %1" : "+v"(u0), "+v"(u2));              \
      asm("v_permlane16_swap_b32 %0, %1" : "+v"(u1), "+v"(u3));              \
      pbA[ks2][0] = u0; pbA[ks2][1] = u1;                                    \
      pbA[ks2][2] = u2; pbA[ks2][3] = u3;                                    \
    }                                                                        \
    VMCNT_BARRIER(WAITN);                                                    \
  } while (0)

  // prologue: V(0)->V[0], K(0)->K[0], K(1)->K[1]; drain V0,K0; K1 in flight
  STAGE_VT(vw0);
  STAGE_KT(kw0);
  STAGE_KT(kw1);
  VMCNT_BARRIER(2);

  // kb=0: no PV; stages V(1)->V[1], K(2)->K[2]; reads K[0]
  ABODY(0, 1, 1, 4, kw2, vw1, kr0, vr0);
  // kb=1..27: 9 groups of 3 (tile t in buf t%3 for both K and V)
  for (int g = 0; g < 9; ++g) {
    ABODY(1, 1, 1, 4, kw0, vw2, kr1, vr0);   // kb%3==1
    ABODY(1, 1, 1, 4, kw1, vw0, kr2, vr1);   // kb%3==2
    ABODY(1, 1, 1, 4, kw2, vw1, kr0, vr2);   // kb%3==0
  }
  // kb=28 (%3==1), kb=29 (%3==2): normal
  ABODY(1, 1, 1, 4, kw0, vw2, kr1, vr0);
  ABODY(1, 1, 1, 4, kw1, vw0, kr2, vr1);
  // kb=30 (%3==0): stage V(31) only (no K(32)); drain down to V(31)'s 2
  ABODY(1, 1, 0, 2, kw2, vw1, kr0, vr2);
  // kb=31 (%3==1): no staging; drain everything before final PV
  ABODY(1, 0, 0, 0, kw0, vw0, kr1, vr0);

  // ---- final lagged PV(31): V[31%3] = V[1] ----
  {
    u32x2 tr[2][4][2];
#pragma unroll
    for (int ks2 = 0; ks2 < 2; ++ks2)
#pragma unroll
      for (int dt = 0; dt < 4; ++dt)
#pragma unroll
        for (int u = 0; u < 2; ++u)
          tr[ks2][dt][u] = ds_tr16(vr1 + dt * 2048 + ks2 * 1024 + u * 512);
    asm volatile("s_waitcnt lgkmcnt(0)" ::: "memory");
    __builtin_amdgcn_sched_barrier(0);
#pragma unroll
    for (int ks2 = 0; ks2 < 2; ++ks2) {
      union { u32x4 u; bf16x8 v; } pb;
      pb.u = pbA[ks2];
#pragma unroll
      for (int dt = 0; dt < 4; ++dt) {
        union { u32x4 u; bf16x8 v; } cv;
        cv.u[0] = tr[ks2][dt][0][0]; cv.u[1] = tr[ks2][dt][0][1];
        cv.u[2] = tr[ks2][dt][1][0]; cv.u[3] = tr[ks2][dt][1][1];
        acc[dt] = __builtin_amdgcn_mfma_f32_16x16x32_bf16(cv.v, pb.v, acc[dt], 0, 0, 0);
      }
    }
  }

  // ---- deferred row-sum + epilogue ----
  l += __shfl_xor(l, 16);
  l += __shfl_xor(l, 32);
  float inv = 1.0f / l;
  size_t orow = ((size_t)b * SEQ + q0 + q) * DM + h * HD + lk * 4;
#pragma unroll
  for (int dt = 0; dt < 4; ++dt) {
    u16x4 o;
#pragma unroll
    for (int r = 0; r < 4; ++r) o[r] = f2bf(acc[dt][r] * inv);
    *(u16x4*)(Ab + orow + dt * 16) = o;
  }
#undef STAGE_VT
#undef STAGE_KT
#undef VMCNT_BARRIER
#undef ABODY
}

// ---------------- LayerNorm (wave per row, bf16 input) ----------------
__global__ void k_ln(const unsigned short* __restrict__ x, const float* __restrict__ gamma,
                     const float* __restrict__ beta, float* __restrict__ out) {
  int tid = threadIdx.x, lane = tid & 63, wave = tid >> 6;
  size_t row = (size_t)blockIdx.x * 4 + wave;
  u16x8 xv = *(const u16x8*)(x + row * DM + lane * 8);
  float v[8];
#pragma unroll
  for (int i = 0; i < 8; ++i) v[i] = bf2f(xv[i]);
  float s  = (v[0]+v[1]) + (v[2]+v[3]) + (v[4]+v[5]) + (v[6]+v[7]);
  float ss = (v[0]*v[0]+v[1]*v[1]) + (v[2]*v[2]+v[3]*v[3])
           + (v[4]*v[4]+v[5]*v[5]) + (v[6]*v[6]+v[7]*v[7]);
#pragma unroll
  for (int off = 1; off < 64; off <<= 1) {
    s  += __shfl_xor(s, off);
    ss += __shfl_xor(ss, off);
  }
  float mu  = s * (1.0f / DM);
  float var = ss * (1.0f / DM) - mu * mu;
  float w = rsqrtf(var + 1e-5f);
  fl4 g0 = *(const fl4*)(gamma + lane*8), g1 = *(const fl4*)(gamma + lane*8 + 4);
  fl4 b0 = *(const fl4*)(beta + lane*8),  b1 = *(const fl4*)(beta + lane*8 + 4);
  fl4 o0, o1;
#pragma unroll
  for (int i = 0; i < 4; ++i) {
    o0[i] = (v[i]     - mu) * w * g0[i] + b0[i];
    o1[i] = (v[4 + i] - mu) * w * g1[i] + b1[i];
  }
  float* orow = out + row * DM + lane * 8;
  *(fl4*)orow = o0;
  *(fl4*)(orow + 4) = o1;
}

extern "C" void kernel_launch(void* const* d_in, const int* in_sizes, int n_in,
                              void* d_out, int out_size, void* d_ws, size_t ws_size,
                              hipStream_t stream) {
  const float* layer_input = (const float*)d_in[0];
  const float* cross       = (const float*)d_in[1];
  const float* Wq   = (const float*)d_in[2];
  const float* bq   = (const float*)d_in[3];
  const float* Wkv  = (const float*)d_in[4];
  const float* bkv  = (const float*)d_in[5];
  const float* Wo   = (const float*)d_in[6];
  const float* bo   = (const float*)d_in[7];
  const float* gamma = (const float*)d_in[8];
  const float* beta  = (const float*)d_in[9];
  float* out = (float*)d_out;

  char* ws = (char*)d_ws;
  unsigned short* Xb   = (unsigned short*)(ws + (size_t)0);
  unsigned short* Cb   = (unsigned short*)(ws + ((size_t)8  << 20));
  unsigned short* Qb   = (unsigned short*)(ws + ((size_t)16 << 20));
  unsigned short* KVb  = (unsigned short*)(ws + ((size_t)24 << 20));
  unsigned short* Abuf = (unsigned short*)(ws + ((size_t)40 << 20));
  unsigned short* tmpb = (unsigned short*)(ws + ((size_t)48 << 20));
  unsigned short* Wqt  = (unsigned short*)(ws + ((size_t)64 << 20));
  unsigned short* Wkvt = (unsigned short*)(ws + ((size_t)65 << 20));
  unsigned short* Wot  = (unsigned short*)(ws + ((size_t)67 << 20));

  // preprocessing: both casts + all 3 weight transposes
  k_pre<<<8448, 256, 0, stream>>>(layer_input, Xb, cross, Cb,
                                  Wq, Wqt, Wkv, Wkvt, Wo, Wot);
  // merged Q + KV projections (Q pre-scaled by 0.125*log2e)
  k_projmm<<<1536, 256, 0, stream>>>(Xb, Cb, Wqt, Wkvt, bq, bkv, Qb, KVb);
  // attention (1024 blocks, XCD-swizzled inside; counted-vmcnt pipeline)
  k_attn<<<1024, 256, 0, stream>>>(Qb, KVb, Abuf);
  // output projection + bias + bf16 residual -> bf16 tmp
  k_omm<<<512, 256, 0, stream>>>(Abuf, Wot, bo, Xb, tmpb);
  // layernorm (bf16 in, f32 out)
  k_ln<<<MTOT/4, 256, 0, stream>>>(tmpb, gamma, beta, out);
}

// Round 18
// 106.410 us; speedup vs baseline: 1.0307x; 1.0307x over previous
//
#include <hip/hip_runtime.h>
#include <hip/hip_bf16.h>
#include <stdint.h>

#define SEQ    2048
#define DM     512
#define NHEAD  8
#define HD     64
#define BATCH  4
#define MTOT   (BATCH*SEQ)   // 8192

typedef __attribute__((ext_vector_type(4))) float  f32x4;
typedef __attribute__((ext_vector_type(8))) short  bf16x8;
typedef __attribute__((ext_vector_type(8))) unsigned short u16x8;
typedef __attribute__((ext_vector_type(4))) unsigned short u16x4;
typedef __attribute__((ext_vector_type(4))) float  fl4;
typedef __attribute__((ext_vector_type(2))) unsigned u32x2;
typedef __attribute__((ext_vector_type(4))) unsigned u32x4;

__device__ __forceinline__ unsigned short f2bf(float f) {
  union { float f; unsigned u; } c; c.f = f;
  return (unsigned short)((c.u + 0x7fffu + ((c.u >> 16) & 1u)) >> 16);
}

__device__ __forceinline__ float bf2f(unsigned short s) {
  unsigned u = (unsigned)s << 16;
  float f; __builtin_memcpy(&f, &u, 4);
  return f;
}

__device__ __forceinline__ void load_lds16(const void* g, void* l) {
  __builtin_amdgcn_global_load_lds((__attribute__((address_space(1))) void*)g,
                                   (__attribute__((address_space(3))) void*)l,
                                   16, 0, 0);
}

// packed f32 pair -> bf16x2 dword (v_cvt_pk_bf16_f32)
__device__ __forceinline__ unsigned pack_bf2(float lo, float hi) {
  __hip_bfloat162 h2 = __float22bfloat162_rn(float2{lo, hi});
  unsigned u; __builtin_memcpy(&u, &h2, 4);
  return u;
}

// ---------------- merged preprocessing: casts + weight transposes -----------
__global__ void k_pre(const float* __restrict__ X, unsigned short* __restrict__ Xb,
                      const float* __restrict__ C, unsigned short* __restrict__ Cb,
                      const float* __restrict__ Wq, unsigned short* __restrict__ Wqt,
                      const float* __restrict__ Wkv, unsigned short* __restrict__ Wkvt,
                      const float* __restrict__ Wo, unsigned short* __restrict__ Wot) {
  __shared__ __align__(16) unsigned short t[64][66];
  int bid = blockIdx.x, tid = threadIdx.x;
  if (bid < 8192) {
    const float* src = (bid < 4096) ? X : C;
    unsigned short* dst = (bid < 4096) ? Xb : Cb;
    int i = (bid & 4095) * 256 + tid;
    fl4 v = *(const fl4*)(src + (size_t)i * 4);
    u32x2 o;
    o[0] = pack_bf2(v[0], v[1]);
    o[1] = pack_bf2(v[2], v[3]);
    *(u32x2*)((void*)(dst + (size_t)i * 4)) = o;
    return;
  }
  int tjob = bid - 8192;
  const float* W; unsigned short* Wt; int Nd, bx, by;
  if (tjob < 64)       { W = Wq;  Wt = Wqt;  Nd = 512;  bx = tjob & 7;  by = tjob >> 3; }
  else if (tjob < 192) { int u = tjob - 64;  W = Wkv; Wt = Wkvt; Nd = 1024; bx = u & 15; by = u >> 4; }
  else                 { int u = tjob - 192; W = Wo;  Wt = Wot;  Nd = 512;  bx = u & 7;  by = u >> 3; }
  int k0 = by * 64, n0 = bx * 64;
  int r = tid >> 2, cs = (tid & 3) * 16;
  const float* src = W + (size_t)(k0 + r) * Nd + n0 + cs;
#pragma unroll
  for (int i = 0; i < 4; ++i) {
    fl4 v = *(const fl4*)(src + i * 4);
    *(unsigned*)&t[r][cs + i*4]     = pack_bf2(v[0], v[1]);
    *(unsigned*)&t[r][cs + i*4 + 2] = pack_bf2(v[2], v[3]);
  }
  __syncthreads();
  unsigned short* drow = Wt + (size_t)(n0 + r) * 512 + k0 + cs;
#pragma unroll
  for (int half = 0; half < 2; ++half) {
    u16x8 o;
#pragma unroll
    for (int i = 0; i < 8; ++i) o[i] = t[cs + half*8 + i][r];
    *(u16x8*)(drow + half * 8) = o;
  }
}

// ------ 128x64-tile GEMM, 2-phase prefetch double-buffered ------------------
// MODE 0: bf16 out with scale. MODE 1: bf16 out = v + bf16 residual.
// MODE 2: V-transposed output -> Vt[bh][dv][tok] via LDS transpose (Als reuse).
template<int MODE>
__device__ __forceinline__ void gemm128x64(
    const unsigned short* __restrict__ A,
    const unsigned short* __restrict__ Bt,
    const float* __restrict__ bias,
    const unsigned short* __restrict__ res,
    unsigned short* __restrict__ Cout,
    int N, int K, int m0, int n0, float osc,
    unsigned short* Als, unsigned short* Bls,
    unsigned short* Vt = nullptr, int bh = 0) {
  int tid  = threadIdx.x;
  int lane = tid & 63, wave = tid >> 6;
  int q = lane & 15, lk = lane >> 4;
  f32x4 acc[2][4];
#pragma unroll
  for (int mt = 0; mt < 2; ++mt)
#pragma unroll
    for (int nt = 0; nt < 4; ++nt) acc[mt][nt] = f32x4{0.f,0.f,0.f,0.f};

  const unsigned short* gA[4];
#pragma unroll
  for (int it = 0; it < 4; ++it) {
    int idx = tid + it * 256;
    int row = idx >> 3, ch = idx & 7, sc = ch ^ (row & 7);
    gA[it] = A + (size_t)(m0 + row) * K + sc * 8;
  }
  const unsigned short* gB[2];
#pragma unroll
  for (int it = 0; it < 2; ++it) {
    int idx = tid + it * 256;
    int row = idx >> 3, ch = idx & 7, sc = ch ^ (row & 7);
    gB[it] = Bt + (size_t)(n0 + row) * K + sc * 8;
  }
  char* aD = (char*)Als + tid * 16;
  char* bD = (char*)Bls + tid * 16;

#pragma unroll
  for (int it = 0; it < 4; ++it) { load_lds16(gA[it], aD + it * 4096); gA[it] += 64; }
#pragma unroll
  for (int it = 0; it < 2; ++it) { load_lds16(gB[it], bD + it * 4096); gB[it] += 64; }
  __syncthreads();

  int nkb = K >> 6;
  int buf = 0;
  for (int kb = 0; kb < nkb; ++kb) {
    if (kb + 1 < nkb) {
      char* aN = aD + (buf ^ 1) * 16384;
      char* bN = bD + (buf ^ 1) * 8192;
#pragma unroll
      for (int it = 0; it < 4; ++it) { load_lds16(gA[it], aN + it * 4096); gA[it] += 64; }
#pragma unroll
      for (int it = 0; it < 2; ++it) { load_lds16(gB[it], bN + it * 4096); gB[it] += 64; }
    }
    const char* aR = (const char*)Als + buf * 16384;
    const char* bR = (const char*)Bls + buf * 8192;
#pragma unroll
    for (int ks = 0; ks < 2; ++ks) {
      bf16x8 a[2], b[4];
#pragma unroll
      for (int mt = 0; mt < 2; ++mt) {
        int row = wave * 32 + mt * 16 + q;
        a[mt] = *(const bf16x8*)(aR + row * 128 + (((ks*4 + lk) ^ (row & 7)) * 16));
      }
#pragma unroll
      for (int nt = 0; nt < 4; ++nt) {
        int row = nt * 16 + q;
        b[nt] = *(const bf16x8*)(bR + row * 128 + (((ks*4 + lk) ^ (row & 7)) * 16));
      }
#pragma unroll
      for (int mt = 0; mt < 2; ++mt)
#pragma unroll
        for (int nt = 0; nt < 4; ++nt)
          acc[mt][nt] = __builtin_amdgcn_mfma_f32_16x16x32_bf16(a[mt], b[nt], acc[mt][nt], 0, 0, 0);
    }
    __syncthreads();
    buf ^= 1;
  }
  if (MODE == 2) {
    // transpose through LDS (reuse Als): T[64 col][pad 136] of u16 rows=128
    unsigned short* T = Als;
#pragma unroll
    for (int nt = 0; nt < 4; ++nt) {
      int coll = nt * 16 + q;
      float bv = bias[n0 + coll];
#pragma unroll
      for (int mt = 0; mt < 2; ++mt) {
        int rowl = wave * 32 + mt * 16 + lk * 4;
#pragma unroll
        for (int rr = 0; rr < 4; ++rr)
          T[coll * 136 + rowl + rr] = f2bf(acc[mt][nt][rr] + bv);
      }
    }
    __syncthreads();
    int dv = tid >> 2, c = tid & 3;
    const unsigned short* s = T + dv * 136 + c * 32;
    unsigned short* d = Vt + ((size_t)bh * 64 + dv) * 2048 + (m0 & 2047) + c * 32;
#pragma unroll
    for (int i = 0; i < 4; ++i)
      *(u16x8*)(d + i * 8) = *(const u16x8*)(s + i * 8);
    return;
  }
#pragma unroll
  for (int nt = 0; nt < 4; ++nt) {
    int col = n0 + nt * 16 + q;
    float bv = bias[col];
#pragma unroll
    for (int mt = 0; mt < 2; ++mt) {
      int rowb = m0 + wave * 32 + mt * 16 + lk * 4;
#pragma unroll
      for (int rr = 0; rr < 4; ++rr) {
        float v = acc[mt][nt][rr] + bv;
        size_t off = (size_t)(rowb + rr) * N + col;
        if (MODE == 1) Cout[off] = f2bf(v + bf2f(res[off]));
        else           Cout[off] = f2bf(v * osc);
      }
    }
  }
}

// merged Q-proj + KV-proj. grid 1536 (XCD-swizzled): l<512 -> Q, else KV.
// KV n-tiles 0..7 = K (into KVb, stride 1024); 8..15 = V (transposed to Vt).
__global__ __launch_bounds__(256, 3)
void k_projmm(const unsigned short* __restrict__ Xb, const unsigned short* __restrict__ Cb,
              const unsigned short* __restrict__ Wqt, const unsigned short* __restrict__ Wkvt,
              const float* __restrict__ bq, const float* __restrict__ bkv,
              unsigned short* __restrict__ Qb, unsigned short* __restrict__ KVb,
              unsigned short* __restrict__ Vt) {
  __shared__ __align__(16) unsigned short Als[2 * 128 * 64];
  __shared__ __align__(16) unsigned short Bls[2 * 64 * 64];
  int bid = blockIdx.x;
  int l = (bid & 7) * 192 + (bid >> 3);
  const float c1 = 0.125f * 1.44269504088896340736f;
  if (l < 512) {
    int m = l >> 3, n = l & 7;
    gemm128x64<0>(Xb, Wqt, bq, nullptr, Qb, 512, 512, m * 128, n * 64, c1, Als, Bls);
  } else {
    int l2 = l - 512;
    int m = l2 >> 4, n = l2 & 15;
    if (n < 8)
      gemm128x64<0>(Cb, Wkvt, bkv, nullptr, KVb, 1024, 512, m * 128, n * 64, 1.0f, Als, Bls);
    else
      gemm128x64<2>(Cb, Wkvt, bkv, nullptr, KVb, 1024, 512, m * 128, n * 64, 1.0f, Als, Bls,
                    Vt, (m >> 4) * 8 + (n - 8));
  }
}

// O-proj + bias + bf16 residual -> bf16 tmp. grid 512 (XCD-swizzled).
__global__ __launch_bounds__(256, 3)
void k_omm(const unsigned short* __restrict__ Abuf, const unsigned short* __restrict__ Wot,
           const float* __restrict__ bo, const unsigned short* __restrict__ residb,
           unsigned short* __restrict__ tmp) {
  __shared__ __align__(16) unsigned short Als[2 * 128 * 64];
  __shared__ __align__(16) unsigned short Bls[2 * 64 * 64];
  int bid = blockIdx.x;
  int l = (bid & 7) * 64 + (bid >> 3);
  int m = l >> 3, n = l & 7;
  gemm128x64<1>(Abuf, Wot, bo, residb, tmp, 512, 512, m * 128, n * 64, 1.0f, Als, Bls);
}

// ---------------- flash attention v16: V^T staging, all-b128 LDS reads -------
// V pre-transposed in global (Vt[bh][dv][tok]); staged like K via
// global_load_lds (pre-swizzled source, linear [64 dv][64 tok] LDS), read as
// 8 XOR-swizzled ds_read_b128 per wave-tile (was 16 ds_read_b64_tr_b16).
// r16 static period-6 schedule, 40 KB LDS (K x2 + V x3), 4 blocks/CU.
// No-max softmax (Q pre-scaled by 0.125*log2e); permlane P-network.
__global__ __launch_bounds__(256, 4)
void k_attn(const unsigned short* __restrict__ Qb,
            const unsigned short* __restrict__ KVb,
            const unsigned short* __restrict__ Vtg,
            unsigned short* __restrict__ Ab) {
  __shared__ __align__(16) unsigned short Klds[2][4096];
  __shared__ __align__(16) unsigned short Vlds[3][4096];
  int tid  = threadIdx.x;
  int lane = tid & 63;
  int q    = lane & 15, lk = lane >> 4;
  int bid = blockIdx.x;
  int swz = (bid & 7) * 128 + (bid >> 3);   // 128 blocks (4 bh) per XCD
  int qt = swz & 31, bh = swz >> 5;
  int b  = bh >> 3, h = bh & 7;
  int q0 = qt * 64 + (tid >> 6) * 16;
  const size_t kvbase = (size_t)b * SEQ * 1024;

  // Q fragments (16 rows per wave)
  bf16x8 qf0, qf1;
  {
    size_t qrow = (size_t)b * SEQ + q0 + q;
    qf0 = *(const bf16x8*)(Qb + qrow * DM + h * HD + lk * 8);
    qf1 = *(const bf16x8*)(Qb + qrow * DM + h * HD + 32 + lk * 8);
  }
  f32x4 acc[4];
#pragma unroll
  for (int i = 0; i < 4; ++i) acc[i] = f32x4{0.f,0.f,0.f,0.f};
  float l = 0.f;            // per-lane partial row-sum (reduced at the end)
  u32x4 pbA[2];

  // ---- staging pointers (K advance 65536 elems/tile; V advance 64) ----
  const unsigned short *gK0, *gK1, *gV0, *gV1;
  {
    int r0 = tid >> 3, s0_ = (tid & 7) ^ (r0 & 7);
    gK0 = KVb + kvbase + (size_t)r0 * 1024 + h * HD + s0_ * 8;
    int i1 = tid + 256, r1 = i1 >> 3, s1_ = (i1 & 7) ^ (r1 & 7);
    gK1 = KVb + kvbase + (size_t)r1 * 1024 + h * HD + s1_ * 8;
    // V^T source: rows are dv (64), cols are tok
    gV0 = Vtg + ((size_t)bh * 64 + r0) * 2048 + s0_ * 8;
    gV1 = Vtg + ((size_t)bh * 64 + r1) * 2048 + s1_ * 8;
  }
  char* kw0 = (char*)Klds[0] + tid * 16;
  char* kw1 = (char*)Klds[1] + tid * 16;
  char* vw0 = (char*)Vlds[0] + tid * 16;
  char* vw1 = (char*)Vlds[1] + tid * 16;
  char* vw2 = (char*)Vlds[2] + tid * 16;
  const char* kr0 = (const char*)Klds[0];
  const char* kr1 = (const char*)Klds[1];
  const char* vr0 = (const char*)Vlds[0];
  const char* vr1 = (const char*)Vlds[1];
  const char* vr2 = (const char*)Vlds[2];

#define STAGE(kd_, vd_) do {                        \
    load_lds16(gK0, (kd_));                         \
    load_lds16(gK1, (kd_) + 4096);                  \
    load_lds16(gV0, (vd_));                         \
    load_lds16(gV1, (vd_) + 4096);                  \
    gK0 += 65536; gK1 += 65536;                     \
    gV0 += 64; gV1 += 64;                           \
  } while (0)

// one tile body; DO_PV/DO_STAGE literal 0/1; buffers are fixed pointers.
#define ABODY(DO_PV, DO_STAGE, kdst_, vdst_, krd_, vprd_) do {               \
    if (DO_STAGE) STAGE(kdst_, vdst_);                                       \
    if (DO_PV) {                                                             \
      bf16x8 vf0[4], vf1[4];                                                 \
      _Pragma("unroll")                                                      \
      for (int dt = 0; dt < 4; ++dt) {                                       \
        int row = dt * 16 + q;                                               \
        vf0[dt] = *(const bf16x8*)((vprd_) + row * 128 + ((lk ^ (q & 7)) * 16)); \
        vf1[dt] = *(const bf16x8*)((vprd_) + row * 128 + (((4 + lk) ^ (q & 7)) * 16)); \
      }                                                                      \
      __builtin_amdgcn_s_setprio(1);                                         \
      {                                                                      \
        union { u32x4 u; bf16x8 v; } pb;                                     \
        pb.u = pbA[0];                                                       \
        _Pragma("unroll")                                                    \
        for (int dt = 0; dt < 4; ++dt)                                       \
          acc[dt] = __builtin_amdgcn_mfma_f32_16x16x32_bf16(vf0[dt], pb.v, acc[dt], 0, 0, 0); \
        pb.u = pbA[1];                                                       \
        _Pragma("unroll")                                                    \
        for (int dt = 0; dt < 4; ++dt)                                       \
          acc[dt] = __builtin_amdgcn_mfma_f32_16x16x32_bf16(vf1[dt], pb.v, acc[dt], 0, 0, 0); \
      }                                                                      \
      __builtin_amdgcn_s_setprio(0);                                         \
    }                                                                        \
    f32x4 st[4];                                                             \
    _Pragma("unroll")                                                        \
    for (int kt = 0; kt < 4; ++kt) st[kt] = f32x4{0.f,0.f,0.f,0.f};          \
    __builtin_amdgcn_s_setprio(1);                                           \
    _Pragma("unroll")                                                        \
    for (int kt = 0; kt < 4; ++kt) {                                         \
      int row = kt * 16 + q;                                                 \
      bf16x8 kf0 = *(const bf16x8*)((krd_) + row * 128 + ((lk ^ (q & 7)) * 16)); \
      bf16x8 kf1 = *(const bf16x8*)((krd_) + row * 128 + (((4 + lk) ^ (q & 7)) * 16)); \
      st[kt] = __builtin_amdgcn_mfma_f32_16x16x32_bf16(kf0, qf0, st[kt], 0, 0, 0); \
      st[kt] = __builtin_amdgcn_mfma_f32_16x16x32_bf16(kf1, qf1, st[kt], 0, 0, 0); \
    }                                                                        \
    __builtin_amdgcn_s_setprio(0);                                           \
    float p[4][4];                                                           \
    _Pragma("unroll")                                                        \
    for (int kt = 0; kt < 4; ++kt)                                           \
      _Pragma("unroll")                                                      \
      for (int r = 0; r < 4; ++r) {                                          \
        float pe = __builtin_amdgcn_exp2f(st[kt][r]);                        \
        p[kt][r] = pe;                                                       \
        l += pe;                                                             \
      }                                                                      \
    _Pragma("unroll")                                                        \
    for (int ks2 = 0; ks2 < 2; ++ks2) {                                      \
      unsigned u0 = pack_bf2(p[2*ks2][0],     p[2*ks2][1]);                  \
      unsigned u1 = pack_bf2(p[2*ks2][2],     p[2*ks2][3]);                  \
      unsigned u2 = pack_bf2(p[2*ks2 + 1][0], p[2*ks2 + 1][1]);              \
      unsigned u3 = pack_bf2(p[2*ks2 + 1][2], p[2*ks2 + 1][3]);              \
      asm("v_permlane32_swap_b32 %0, %1" : "+v"(u0), "+v"(u2));              \
      asm("v_permlane32_swap_b32 %0, %1" : "+v"(u1), "+v"(u3));              \
      asm("v_permlane16_swap_b32 %0, %1" : "+v"(u0), "+v"(u2));              \
      asm("v_permlane16_swap_b32 %0, %1" : "+v"(u1), "+v"(u3));              \
      pbA[ks2][0] = u0; pbA[ks2][1] = u1;                                    \
      pbA[ks2][2] = u2; pbA[ks2][3] = u3;                                    \
    }                                                                        \
    __syncthreads();                                                         \
  } while (0)

  // prologue: tile 0 -> K[0], V[0]
  STAGE(kw0, vw0);
  __syncthreads();

  // kb=0 (peeled: stages tile 1 -> K[1], V[1]; no PV)
  ABODY(0, 1, kw1, vw1, kr0, vr0);
  // kb=1..30: 5 groups of 6 (V tile t in buffer t%3; K tile t in buffer t%2)
  for (int g = 0; g < 5; ++g) {
    ABODY(1, 1, kw0, vw2, kr1, vr0);   // kb%6==1
    ABODY(1, 1, kw1, vw0, kr0, vr1);   // kb%6==2
    ABODY(1, 1, kw0, vw1, kr1, vr2);   // kb%6==3
    ABODY(1, 1, kw1, vw2, kr0, vr0);   // kb%6==4
    ABODY(1, 1, kw0, vw0, kr1, vr1);   // kb%6==5
    ABODY(1, 1, kw1, vw1, kr0, vr2);   // kb%6==0
  }
  // kb=31 (peeled: no stage; K read buf 1, PV source V[30%3]=V[0])
  ABODY(1, 0, kw0, vw0, kr1, vr0);

  // ---- final lagged PV(31): V[31%3] = V[1] ----
  {
    bf16x8 vf0[4], vf1[4];
#pragma unroll
    for (int dt = 0; dt < 4; ++dt) {
      int row = dt * 16 + q;
      vf0[dt] = *(const bf16x8*)(vr1 + row * 128 + ((lk ^ (q & 7)) * 16));
      vf1[dt] = *(const bf16x8*)(vr1 + row * 128 + (((4 + lk) ^ (q & 7)) * 16));
    }
    union { u32x4 u; bf16x8 v; } pb;
    pb.u = pbA[0];
#pragma unroll
    for (int dt = 0; dt < 4; ++dt)
      acc[dt] = __builtin_amdgcn_mfma_f32_16x16x32_bf16(vf0[dt], pb.v, acc[dt], 0, 0, 0);
    pb.u = pbA[1];
#pragma unroll
    for (int dt = 0; dt < 4; ++dt)
      acc[dt] = __builtin_amdgcn_mfma_f32_16x16x32_bf16(vf1[dt], pb.v, acc[dt], 0, 0, 0);
  }

  // ---- deferred row-sum + epilogue ----
  l += __shfl_xor(l, 16);
  l += __shfl_xor(l, 32);
  float inv = 1.0f / l;
  size_t orow = ((size_t)b * SEQ + q0 + q) * DM + h * HD + lk * 4;
#pragma unroll
  for (int dt = 0; dt < 4; ++dt) {
    u16x4 o;
#pragma unroll
    for (int r = 0; r < 4; ++r) o[r] = f2bf(acc[dt][r] * inv);
    *(u16x4*)(Ab + orow + dt * 16) = o;
  }
#undef STAGE
#undef ABODY
}

// ---------------- LayerNorm (wave per row, bf16 input) ----------------
__global__ void k_ln(const unsigned short* __restrict__ x, const float* __restrict__ gamma,
                     const float* __restrict__ beta, float* __restrict__ out) {
  int tid = threadIdx.x, lane = tid & 63, wave = tid >> 6;
  size_t row = (size_t)blockIdx.x * 4 + wave;
  u16x8 xv = *(const u16x8*)(x + row * DM + lane * 8);
  float v[8];
#pragma unroll
  for (int i = 0; i < 8; ++i) v[i] = bf2f(xv[i]);
  float s  = (v[0]+v[1]) + (v[2]+v[3]) + (v[4]+v[5]) + (v[6]+v[7]);
  float ss = (v[0]*v[0]+v[1]*v[1]) + (v[2]*v[2]+v[3]*v[3])
           + (v[4]*v[4]+v[5]*v[5]) + (v[6]*v[6]+v[7]*v[7]);
#pragma unroll
  for (int off = 1; off < 64; off <<= 1) {
    s  += __shfl_xor(s, off);
    ss += __shfl_xor(ss, off);
  }
  float mu  = s * (1.0f / DM);
  float var = ss * (1.0f / DM) - mu * mu;
  float w = rsqrtf(var + 1e-5f);
  fl4 g0 = *(const fl4*)(gamma + lane*8), g1 = *(const fl4*)(gamma + lane*8 + 4);
  fl4 b0 = *(const fl4*)(beta + lane*8),  b1 = *(const fl4*)(beta + lane*8 + 4);
  fl4 o0, o1;
#pragma unroll
  for (int i = 0; i < 4; ++i) {
    o0[i] = (v[i]     - mu) * w * g0[i] + b0[i];
    o1[i] = (v[4 + i] - mu) * w * g1[i] + b1[i];
  }
  float* orow = out + row * DM + lane * 8;
  *(fl4*)orow = o0;
  *(fl4*)(orow + 4) = o1;
}

extern "C" void kernel_launch(void* const* d_in, const int* in_sizes, int n_in,
                              void* d_out, int out_size, void* d_ws, size_t ws_size,
                              hipStream_t stream) {
  const float* layer_input = (const float*)d_in[0];
  const float* cross       = (const float*)d_in[1];
  const float* Wq   = (const float*)d_in[2];
  const float* bq   = (const float*)d_in[3];
  const float* Wkv  = (const float*)d_in[4];
  const float* bkv  = (const float*)d_in[5];
  const float* Wo   = (const float*)d_in[6];
  const float* bo   = (const float*)d_in[7];
  const float* gamma = (const float*)d_in[8];
  const float* beta  = (const float*)d_in[9];
  float* out = (float*)d_out;

  char* ws = (char*)d_ws;
  unsigned short* Xb   = (unsigned short*)(ws + (size_t)0);
  unsigned short* Cb   = (unsigned short*)(ws + ((size_t)8  << 20));
  unsigned short* Qb   = (unsigned short*)(ws + ((size_t)16 << 20));
  unsigned short* KVb  = (unsigned short*)(ws + ((size_t)24 << 20));
  unsigned short* Abuf = (unsigned short*)(ws + ((size_t)40 << 20));
  // Vt aliases tmpb's region: written by projmm, consumed by attn, dead
  // before k_omm writes tmpb (stream-serialized).
  unsigned short* Vt   = (unsigned short*)(ws + ((size_t)48 << 20));
  unsigned short* tmpb = (unsigned short*)(ws + ((size_t)48 << 20));
  unsigned short* Wqt  = (unsigned short*)(ws + ((size_t)64 << 20));
  unsigned short* Wkvt = (unsigned short*)(ws + ((size_t)65 << 20));
  unsigned short* Wot  = (unsigned short*)(ws + ((size_t)67 << 20));

  // preprocessing: both casts + all 3 weight transposes
  k_pre<<<8448, 256, 0, stream>>>(layer_input, Xb, cross, Cb,
                                  Wq, Wqt, Wkv, Wkvt, Wo, Wot);
  // merged Q + KV projections (Q pre-scaled by 0.125*log2e; V transposed)
  k_projmm<<<1536, 256, 0, stream>>>(Xb, Cb, Wqt, Wkvt, bq, bkv, Qb, KVb, Vt);
  // attention (1024 blocks, XCD-swizzled inside; 4 blocks/CU)
  k_attn<<<1024, 256, 0, stream>>>(Qb, KVb, Vt, Abuf);
  // output projection + bias + bf16 residual -> bf16 tmp
  k_omm<<<512, 256, 0, stream>>>(Abuf, Wot, bo, Xb, tmpb);
  // layernorm (bf16 in, f32 out)
  k_ln<<<MTOT/4, 256, 0, stream>>>(tmpb, gamma, beta, out);
}

// Round 19
// 99.789 us; speedup vs baseline: 1.0990x; 1.0663x over previous
//
#include <hip/hip_runtime.h>
#include <hip/hip_bf16.h>
#include <stdint.h>

#define SEQ    2048
#define DM     512
#define NHEAD  8
#define HD     64
#define BATCH  4
#define MTOT   (BATCH*SEQ)   // 8192

typedef __attribute__((ext_vector_type(4))) float  f32x4;
typedef __attribute__((ext_vector_type(8))) short  bf16x8;
typedef __attribute__((ext_vector_type(8))) unsigned short u16x8;
typedef __attribute__((ext_vector_type(4))) unsigned short u16x4;
typedef __attribute__((ext_vector_type(4))) float  fl4;
typedef __attribute__((ext_vector_type(2))) unsigned u32x2;
typedef __attribute__((ext_vector_type(4))) unsigned u32x4;

__device__ __forceinline__ unsigned short f2bf(float f) {
  union { float f; unsigned u; } c; c.f = f;
  return (unsigned short)((c.u + 0x7fffu + ((c.u >> 16) & 1u)) >> 16);
}

__device__ __forceinline__ float bf2f(unsigned short s) {
  unsigned u = (unsigned)s << 16;
  float f; __builtin_memcpy(&f, &u, 4);
  return f;
}

__device__ __forceinline__ void load_lds16(const void* g, void* l) {
  __builtin_amdgcn_global_load_lds((__attribute__((address_space(1))) void*)g,
                                   (__attribute__((address_space(3))) void*)l,
                                   16, 0, 0);
}

// packed f32 pair -> bf16x2 dword (v_cvt_pk_bf16_f32)
__device__ __forceinline__ unsigned pack_bf2(float lo, float hi) {
  __hip_bfloat162 h2 = __float22bfloat162_rn(float2{lo, hi});
  unsigned u; __builtin_memcpy(&u, &h2, 4);
  return u;
}

// ---------------- merged preprocessing: casts + weight transposes -----------
__global__ void k_pre(const float* __restrict__ X, unsigned short* __restrict__ Xb,
                      const float* __restrict__ C, unsigned short* __restrict__ Cb,
                      const float* __restrict__ Wq, unsigned short* __restrict__ Wqt,
                      const float* __restrict__ Wkv, unsigned short* __restrict__ Wkvt,
                      const float* __restrict__ Wo, unsigned short* __restrict__ Wot) {
  __shared__ __align__(16) unsigned short t[64][66];
  int bid = blockIdx.x, tid = threadIdx.x;
  if (bid < 8192) {
    const float* src = (bid < 4096) ? X : C;
    unsigned short* dst = (bid < 4096) ? Xb : Cb;
    int i = (bid & 4095) * 256 + tid;
    fl4 v = *(const fl4*)(src + (size_t)i * 4);
    u32x2 o;
    o[0] = pack_bf2(v[0], v[1]);
    o[1] = pack_bf2(v[2], v[3]);
    *(u32x2*)((void*)(dst + (size_t)i * 4)) = o;
    return;
  }
  int tjob = bid - 8192;
  const float* W; unsigned short* Wt; int Nd, bx, by;
  if (tjob < 64)       { W = Wq;  Wt = Wqt;  Nd = 512;  bx = tjob & 7;  by = tjob >> 3; }
  else if (tjob < 192) { int u = tjob - 64;  W = Wkv; Wt = Wkvt; Nd = 1024; bx = u & 15; by = u >> 4; }
  else                 { int u = tjob - 192; W = Wo;  Wt = Wot;  Nd = 512;  bx = u & 7;  by = u >> 3; }
  int k0 = by * 64, n0 = bx * 64;
  int r = tid >> 2, cs = (tid & 3) * 16;
  const float* src = W + (size_t)(k0 + r) * Nd + n0 + cs;
#pragma unroll
  for (int i = 0; i < 4; ++i) {
    fl4 v = *(const fl4*)(src + i * 4);
    *(unsigned*)&t[r][cs + i*4]     = pack_bf2(v[0], v[1]);
    *(unsigned*)&t[r][cs + i*4 + 2] = pack_bf2(v[2], v[3]);
  }
  __syncthreads();
  unsigned short* drow = Wt + (size_t)(n0 + r) * 512 + k0 + cs;
#pragma unroll
  for (int half = 0; half < 2; ++half) {
    u16x8 o;
#pragma unroll
    for (int i = 0; i < 8; ++i) o[i] = t[cs + half*8 + i][r];
    *(u16x8*)(drow + half * 8) = o;
  }
}

// ------ 128x64-tile GEMM, 2-phase prefetch double-buffered ------------------
// MODE 0: bf16 out with scale. MODE 1: bf16 out = v + bf16 residual.
// MODE 2: V-transposed output -> Vt[bh][dv][tok] via LDS transpose (Als reuse).
template<int MODE>
__device__ __forceinline__ void gemm128x64(
    const unsigned short* __restrict__ A,
    const unsigned short* __restrict__ Bt,
    const float* __restrict__ bias,
    const unsigned short* __restrict__ res,
    unsigned short* __restrict__ Cout,
    int N, int K, int m0, int n0, float osc,
    unsigned short* Als, unsigned short* Bls,
    unsigned short* Vt = nullptr, int bh = 0) {
  int tid  = threadIdx.x;
  int lane = tid & 63, wave = tid >> 6;
  int q = lane & 15, lk = lane >> 4;
  f32x4 acc[2][4];
#pragma unroll
  for (int mt = 0; mt < 2; ++mt)
#pragma unroll
    for (int nt = 0; nt < 4; ++nt) acc[mt][nt] = f32x4{0.f,0.f,0.f,0.f};

  const unsigned short* gA[4];
#pragma unroll
  for (int it = 0; it < 4; ++it) {
    int idx = tid + it * 256;
    int row = idx >> 3, ch = idx & 7, sc = ch ^ (row & 7);
    gA[it] = A + (size_t)(m0 + row) * K + sc * 8;
  }
  const unsigned short* gB[2];
#pragma unroll
  for (int it = 0; it < 2; ++it) {
    int idx = tid + it * 256;
    int row = idx >> 3, ch = idx & 7, sc = ch ^ (row & 7);
    gB[it] = Bt + (size_t)(n0 + row) * K + sc * 8;
  }
  char* aD = (char*)Als + tid * 16;
  char* bD = (char*)Bls + tid * 16;

#pragma unroll
  for (int it = 0; it < 4; ++it) { load_lds16(gA[it], aD + it * 4096); gA[it] += 64; }
#pragma unroll
  for (int it = 0; it < 2; ++it) { load_lds16(gB[it], bD + it * 4096); gB[it] += 64; }
  __syncthreads();

  int nkb = K >> 6;
  int buf = 0;
  for (int kb = 0; kb < nkb; ++kb) {
    if (kb + 1 < nkb) {
      char* aN = aD + (buf ^ 1) * 16384;
      char* bN = bD + (buf ^ 1) * 8192;
#pragma unroll
      for (int it = 0; it < 4; ++it) { load_lds16(gA[it], aN + it * 4096); gA[it] += 64; }
#pragma unroll
      for (int it = 0; it < 2; ++it) { load_lds16(gB[it], bN + it * 4096); gB[it] += 64; }
    }
    const char* aR = (const char*)Als + buf * 16384;
    const char* bR = (const char*)Bls + buf * 8192;
#pragma unroll
    for (int ks = 0; ks < 2; ++ks) {
      bf16x8 a[2], b[4];
#pragma unroll
      for (int mt = 0; mt < 2; ++mt) {
        int row = wave * 32 + mt * 16 + q;
        a[mt] = *(const bf16x8*)(aR + row * 128 + (((ks*4 + lk) ^ (row & 7)) * 16));
      }
#pragma unroll
      for (int nt = 0; nt < 4; ++nt) {
        int row = nt * 16 + q;
        b[nt] = *(const bf16x8*)(bR + row * 128 + (((ks*4 + lk) ^ (row & 7)) * 16));
      }
#pragma unroll
      for (int mt = 0; mt < 2; ++mt)
#pragma unroll
        for (int nt = 0; nt < 4; ++nt)
          acc[mt][nt] = __builtin_amdgcn_mfma_f32_16x16x32_bf16(a[mt], b[nt], acc[mt][nt], 0, 0, 0);
    }
    __syncthreads();
    buf ^= 1;
  }
  if (MODE == 2) {
    // transpose through LDS (reuse Als): T[64 col][pad 136] of u16 rows=128
    unsigned short* T = Als;
#pragma unroll
    for (int nt = 0; nt < 4; ++nt) {
      int coll = nt * 16 + q;
      float bv = bias[n0 + coll];
#pragma unroll
      for (int mt = 0; mt < 2; ++mt) {
        int rowl = wave * 32 + mt * 16 + lk * 4;
#pragma unroll
        for (int rr = 0; rr < 4; ++rr)
          T[coll * 136 + rowl + rr] = f2bf(acc[mt][nt][rr] + bv);
      }
    }
    __syncthreads();
    int dv = tid >> 2, c = tid & 3;
    const unsigned short* s = T + dv * 136 + c * 32;
    unsigned short* d = Vt + ((size_t)bh * 64 + dv) * 2048 + (m0 & 2047) + c * 32;
#pragma unroll
    for (int i = 0; i < 4; ++i)
      *(u16x8*)(d + i * 8) = *(const u16x8*)(s + i * 8);
    return;
  }
#pragma unroll
  for (int nt = 0; nt < 4; ++nt) {
    int col = n0 + nt * 16 + q;
    float bv = bias[col];
#pragma unroll
    for (int mt = 0; mt < 2; ++mt) {
      int rowb = m0 + wave * 32 + mt * 16 + lk * 4;
#pragma unroll
      for (int rr = 0; rr < 4; ++rr) {
        float v = acc[mt][nt][rr] + bv;
        size_t off = (size_t)(rowb + rr) * N + col;
        if (MODE == 1) Cout[off] = f2bf(v + bf2f(res[off]));
        else           Cout[off] = f2bf(v * osc);
      }
    }
  }
}

// merged Q-proj + KV-proj. grid 1536 (XCD-swizzled): l<512 -> Q, else KV.
// KV n-tiles 0..7 = K (into KVb, stride 1024); 8..15 = V (transposed to Vt).
__global__ __launch_bounds__(256, 3)
void k_projmm(const unsigned short* __restrict__ Xb, const unsigned short* __restrict__ Cb,
              const unsigned short* __restrict__ Wqt, const unsigned short* __restrict__ Wkvt,
              const float* __restrict__ bq, const float* __restrict__ bkv,
              unsigned short* __restrict__ Qb, unsigned short* __restrict__ KVb,
              unsigned short* __restrict__ Vt) {
  __shared__ __align__(16) unsigned short Als[2 * 128 * 64];
  __shared__ __align__(16) unsigned short Bls[2 * 64 * 64];
  int bid = blockIdx.x;
  int l = (bid & 7) * 192 + (bid >> 3);
  const float c1 = 0.125f * 1.44269504088896340736f;
  if (l < 512) {
    int m = l >> 3, n = l & 7;
    gemm128x64<0>(Xb, Wqt, bq, nullptr, Qb, 512, 512, m * 128, n * 64, c1, Als, Bls);
  } else {
    int l2 = l - 512;
    int m = l2 >> 4, n = l2 & 15;
    if (n < 8)
      gemm128x64<0>(Cb, Wkvt, bkv, nullptr, KVb, 1024, 512, m * 128, n * 64, 1.0f, Als, Bls);
    else
      gemm128x64<2>(Cb, Wkvt, bkv, nullptr, KVb, 1024, 512, m * 128, n * 64, 1.0f, Als, Bls,
                    Vt, (m >> 4) * 8 + (n - 8));
  }
}

// O-proj + bias + bf16 residual -> bf16 tmp. grid 512 (XCD-swizzled).
__global__ __launch_bounds__(256, 3)
void k_omm(const unsigned short* __restrict__ Abuf, const unsigned short* __restrict__ Wot,
           const float* __restrict__ bo, const unsigned short* __restrict__ residb,
           unsigned short* __restrict__ tmp) {
  __shared__ __align__(16) unsigned short Als[2 * 128 * 64];
  __shared__ __align__(16) unsigned short Bls[2 * 64 * 64];
  int bid = blockIdx.x;
  int l = (bid & 7) * 64 + (bid >> 3);
  int m = l >> 3, n = l & 7;
  gemm128x64<1>(Abuf, Wot, bo, residb, tmp, 512, 512, m * 128, n * 64, 1.0f, Als, Bls);
}

// ---------------- flash attention v17: 32 q-rows/wave, V^T b128 staging ------
// grid 512 (XCD-swizzled): 32 (b,h) * 16 q-tiles(128); 4 waves * 32 q-rows.
// K/V LDS fragments are shared by BOTH q-subtiles of each wave (DS cycles per
// unit work halved vs 16q/wave — DS pipe was ~78% busy). V pre-transposed in
// global, staged like K, read as XOR-swizzled ds_read_b128. Static period-6
// schedule, 40 KB LDS. No-max softmax; permlane P-network per subtile.
__global__ __launch_bounds__(256, 2)
void k_attn(const unsigned short* __restrict__ Qb,
            const unsigned short* __restrict__ KVb,
            const unsigned short* __restrict__ Vtg,
            unsigned short* __restrict__ Ab) {
  __shared__ __align__(16) unsigned short Klds[2][4096];
  __shared__ __align__(16) unsigned short Vlds[3][4096];
  int tid  = threadIdx.x;
  int lane = tid & 63;
  int q    = lane & 15, lk = lane >> 4;
  int bid = blockIdx.x;
  int swz = (bid & 7) * 64 + (bid >> 3);    // 64 blocks (4 bh) per XCD
  int qt = swz & 15, bh = swz >> 4;
  int b  = bh >> 3, h = bh & 7;
  int q0 = qt * 128 + (tid >> 6) * 32;
  const size_t kvbase = (size_t)b * SEQ * 1024;

  // Q fragments: 2 subtiles of 16 rows each
  bf16x8 qf[2][2];
#pragma unroll
  for (int qh = 0; qh < 2; ++qh) {
    size_t qrow = (size_t)b * SEQ + q0 + qh * 16 + q;
    qf[qh][0] = *(const bf16x8*)(Qb + qrow * DM + h * HD + lk * 8);
    qf[qh][1] = *(const bf16x8*)(Qb + qrow * DM + h * HD + 32 + lk * 8);
  }
  f32x4 acc[2][4];
#pragma unroll
  for (int qh = 0; qh < 2; ++qh)
#pragma unroll
    for (int i = 0; i < 4; ++i) acc[qh][i] = f32x4{0.f,0.f,0.f,0.f};
  float l0 = 0.f, l1 = 0.f;
  u32x4 pbA[2][2];   // [qh][ks2]

  // ---- staging pointers (K advance 65536 elems/tile; V advance 64) ----
  const unsigned short *gK0, *gK1, *gV0, *gV1;
  {
    int r0 = tid >> 3, s0_ = (tid & 7) ^ (r0 & 7);
    gK0 = KVb + kvbase + (size_t)r0 * 1024 + h * HD + s0_ * 8;
    int i1 = tid + 256, r1 = i1 >> 3, s1_ = (i1 & 7) ^ (r1 & 7);
    gK1 = KVb + kvbase + (size_t)r1 * 1024 + h * HD + s1_ * 8;
    gV0 = Vtg + ((size_t)bh * 64 + r0) * 2048 + s0_ * 8;
    gV1 = Vtg + ((size_t)bh * 64 + r1) * 2048 + s1_ * 8;
  }
  char* kw0 = (char*)Klds[0] + tid * 16;
  char* kw1 = (char*)Klds[1] + tid * 16;
  char* vw0 = (char*)Vlds[0] + tid * 16;
  char* vw1 = (char*)Vlds[1] + tid * 16;
  char* vw2 = (char*)Vlds[2] + tid * 16;
  const char* kr0 = (const char*)Klds[0];
  const char* kr1 = (const char*)Klds[1];
  const char* vr0 = (const char*)Vlds[0];
  const char* vr1 = (const char*)Vlds[1];
  const char* vr2 = (const char*)Vlds[2];

#define STAGE(kd_, vd_) do {                        \
    load_lds16(gK0, (kd_));                         \
    load_lds16(gK1, (kd_) + 4096);                  \
    load_lds16(gV0, (vd_));                         \
    load_lds16(gV1, (vd_) + 4096);                  \
    gK0 += 65536; gK1 += 65536;                     \
    gV0 += 64; gV1 += 64;                           \
  } while (0)

// one tile body; DO_PV/DO_STAGE literal 0/1; buffers are fixed pointers.
// V/K fragment ds_reads shared across both q-subtiles.
#define ABODY(DO_PV, DO_STAGE, kdst_, vdst_, krd_, vprd_) do {               \
    if (DO_STAGE) STAGE(kdst_, vdst_);                                       \
    if (DO_PV) {                                                             \
      bf16x8 vf0[4], vf1[4];                                                 \
      _Pragma("unroll")                                                      \
      for (int dt = 0; dt < 4; ++dt) {                                       \
        int row = dt * 16 + q;                                               \
        vf0[dt] = *(const bf16x8*)((vprd_) + row * 128 + ((lk ^ (q & 7)) * 16)); \
        vf1[dt] = *(const bf16x8*)((vprd_) + row * 128 + (((4 + lk) ^ (q & 7)) * 16)); \
      }                                                                      \
      __builtin_amdgcn_s_setprio(1);                                         \
      {                                                                      \
        union { u32x4 u; bf16x8 v; } pb;                                     \
        _Pragma("unroll")                                                    \
        for (int qh = 0; qh < 2; ++qh) {                                     \
          pb.u = pbA[qh][0];                                                 \
          _Pragma("unroll")                                                  \
          for (int dt = 0; dt < 4; ++dt)                                     \
            acc[qh][dt] = __builtin_amdgcn_mfma_f32_16x16x32_bf16(vf0[dt], pb.v, acc[qh][dt], 0, 0, 0); \
          pb.u = pbA[qh][1];                                                 \
          _Pragma("unroll")                                                  \
          for (int dt = 0; dt < 4; ++dt)                                     \
            acc[qh][dt] = __builtin_amdgcn_mfma_f32_16x16x32_bf16(vf1[dt], pb.v, acc[qh][dt], 0, 0, 0); \
        }                                                                    \
      }                                                                      \
      __builtin_amdgcn_s_setprio(0);                                         \
    }                                                                        \
    f32x4 st[2][4];                                                          \
    _Pragma("unroll")                                                        \
    for (int qh = 0; qh < 2; ++qh)                                           \
      _Pragma("unroll")                                                      \
      for (int kt = 0; kt < 4; ++kt) st[qh][kt] = f32x4{0.f,0.f,0.f,0.f};    \
    __builtin_amdgcn_s_setprio(1);                                           \
    _Pragma("unroll")                                                        \
    for (int kt = 0; kt < 4; ++kt) {                                         \
      int row = kt * 16 + q;                                                 \
      bf16x8 kf0 = *(const bf16x8*)((krd_) + row * 128 + ((lk ^ (q & 7)) * 16)); \
      bf16x8 kf1 = *(const bf16x8*)((krd_) + row * 128 + (((4 + lk) ^ (q & 7)) * 16)); \
      st[0][kt] = __builtin_amdgcn_mfma_f32_16x16x32_bf16(kf0, qf[0][0], st[0][kt], 0, 0, 0); \
      st[0][kt] = __builtin_amdgcn_mfma_f32_16x16x32_bf16(kf1, qf[0][1], st[0][kt], 0, 0, 0); \
      st[1][kt] = __builtin_amdgcn_mfma_f32_16x16x32_bf16(kf0, qf[1][0], st[1][kt], 0, 0, 0); \
      st[1][kt] = __builtin_amdgcn_mfma_f32_16x16x32_bf16(kf1, qf[1][1], st[1][kt], 0, 0, 0); \
    }                                                                        \
    __builtin_amdgcn_s_setprio(0);                                           \
    _Pragma("unroll")                                                        \
    for (int qh = 0; qh < 2; ++qh) {                                         \
      float p[4][4];                                                         \
      _Pragma("unroll")                                                      \
      for (int kt = 0; kt < 4; ++kt)                                         \
        _Pragma("unroll")                                                    \
        for (int r = 0; r < 4; ++r) {                                        \
          float pe = __builtin_amdgcn_exp2f(st[qh][kt][r]);                  \
          p[kt][r] = pe;                                                     \
          if (qh) l1 += pe; else l0 += pe;                                   \
        }                                                                    \
      _Pragma("unroll")                                                      \
      for (int ks2 = 0; ks2 < 2; ++ks2) {                                    \
        unsigned u0 = pack_bf2(p[2*ks2][0],     p[2*ks2][1]);                \
        unsigned u1 = pack_bf2(p[2*ks2][2],     p[2*ks2][3]);                \
        unsigned u2 = pack_bf2(p[2*ks2 + 1][0], p[2*ks2 + 1][1]);            \
        unsigned u3 = pack_bf2(p[2*ks2 + 1][2], p[2*ks2 + 1][3]);            \
        asm("v_permlane32_swap_b32 %0, %1" : "+v"(u0), "+v"(u2));            \
        asm("v_permlane32_swap_b32 %0, %1" : "+v"(u1), "+v"(u3));            \
        asm("v_permlane16_swap_b32 %0, %1" : "+v"(u0), "+v"(u2));            \
        asm("v_permlane16_swap_b32 %0, %1" : "+v"(u1), "+v"(u3));            \
        pbA[qh][ks2][0] = u0; pbA[qh][ks2][1] = u1;                          \
        pbA[qh][ks2][2] = u2; pbA[qh][ks2][3] = u3;                          \
      }                                                                      \
    }                                                                        \
    __syncthreads();                                                         \
  } while (0)

  // prologue: tile 0 -> K[0], V[0]
  STAGE(kw0, vw0);
  __syncthreads();

  // kb=0 (peeled: stages tile 1 -> K[1], V[1]; no PV)
  ABODY(0, 1, kw1, vw1, kr0, vr0);
  // kb=1..30: 5 groups of 6 (V tile t in buffer t%3; K tile t in buffer t%2)
  for (int g = 0; g < 5; ++g) {
    ABODY(1, 1, kw0, vw2, kr1, vr0);   // kb%6==1
    ABODY(1, 1, kw1, vw0, kr0, vr1);   // kb%6==2
    ABODY(1, 1, kw0, vw1, kr1, vr2);   // kb%6==3
    ABODY(1, 1, kw1, vw2, kr0, vr0);   // kb%6==4
    ABODY(1, 1, kw0, vw0, kr1, vr1);   // kb%6==5
    ABODY(1, 1, kw1, vw1, kr0, vr2);   // kb%6==0
  }
  // kb=31 (peeled: no stage; K read buf 1, PV source V[30%3]=V[0])
  ABODY(1, 0, kw0, vw0, kr1, vr0);

  // ---- final lagged PV(31): V[31%3] = V[1] ----
  {
    bf16x8 vf0[4], vf1[4];
#pragma unroll
    for (int dt = 0; dt < 4; ++dt) {
      int row = dt * 16 + q;
      vf0[dt] = *(const bf16x8*)(vr1 + row * 128 + ((lk ^ (q & 7)) * 16));
      vf1[dt] = *(const bf16x8*)(vr1 + row * 128 + (((4 + lk) ^ (q & 7)) * 16));
    }
    union { u32x4 u; bf16x8 v; } pb;
#pragma unroll
    for (int qh = 0; qh < 2; ++qh) {
      pb.u = pbA[qh][0];
#pragma unroll
      for (int dt = 0; dt < 4; ++dt)
        acc[qh][dt] = __builtin_amdgcn_mfma_f32_16x16x32_bf16(vf0[dt], pb.v, acc[qh][dt], 0, 0, 0);
      pb.u = pbA[qh][1];
#pragma unroll
      for (int dt = 0; dt < 4; ++dt)
        acc[qh][dt] = __builtin_amdgcn_mfma_f32_16x16x32_bf16(vf1[dt], pb.v, acc[qh][dt], 0, 0, 0);
    }
  }

  // ---- deferred row-sums + epilogue (per subtile) ----
#pragma unroll
  for (int qh = 0; qh < 2; ++qh) {
    float lv = qh ? l1 : l0;
    lv += __shfl_xor(lv, 16);
    lv += __shfl_xor(lv, 32);
    float inv = 1.0f / lv;
    size_t orow = ((size_t)b * SEQ + q0 + qh * 16 + q) * DM + h * HD + lk * 4;
#pragma unroll
    for (int dt = 0; dt < 4; ++dt) {
      u16x4 o;
#pragma unroll
      for (int r = 0; r < 4; ++r) o[r] = f2bf(acc[qh][dt][r] * inv);
      *(u16x4*)(Ab + orow + dt * 16) = o;
    }
  }
#undef STAGE
#undef ABODY
}

// ---------------- LayerNorm (wave per row, bf16 input) ----------------
__global__ void k_ln(const unsigned short* __restrict__ x, const float* __restrict__ gamma,
                     const float* __restrict__ beta, float* __restrict__ out) {
  int tid = threadIdx.x, lane = tid & 63, wave = tid >> 6;
  size_t row = (size_t)blockIdx.x * 4 + wave;
  u16x8 xv = *(const u16x8*)(x + row * DM + lane * 8);
  float v[8];
#pragma unroll
  for (int i = 0; i < 8; ++i) v[i] = bf2f(xv[i]);
  float s  = (v[0]+v[1]) + (v[2]+v[3]) + (v[4]+v[5]) + (v[6]+v[7]);
  float ss = (v[0]*v[0]+v[1]*v[1]) + (v[2]*v[2]+v[3]*v[3])
           + (v[4]*v[4]+v[5]*v[5]) + (v[6]*v[6]+v[7]*v[7]);
#pragma unroll
  for (int off = 1; off < 64; off <<= 1) {
    s  += __shfl_xor(s, off);
    ss += __shfl_xor(ss, off);
  }
  float mu  = s * (1.0f / DM);
  float var = ss * (1.0f / DM) - mu * mu;
  float w = rsqrtf(var + 1e-5f);
  fl4 g0 = *(const fl4*)(gamma + lane*8), g1 = *(const fl4*)(gamma + lane*8 + 4);
  fl4 b0 = *(const fl4*)(beta + lane*8),  b1 = *(const fl4*)(beta + lane*8 + 4);
  fl4 o0, o1;
#pragma unroll
  for (int i = 0; i < 4; ++i) {
    o0[i] = (v[i]     - mu) * w * g0[i] + b0[i];
    o1[i] = (v[4 + i] - mu) * w * g1[i] + b1[i];
  }
  float* orow = out + row * DM + lane * 8;
  *(fl4*)orow = o0;
  *(fl4*)(orow + 4) = o1;
}

extern "C" void kernel_launch(void* const* d_in, const int* in_sizes, int n_in,
                              void* d_out, int out_size, void* d_ws, size_t ws_size,
                              hipStream_t stream) {
  const float* layer_input = (const float*)d_in[0];
  const float* cross       = (const float*)d_in[1];
  const float* Wq   = (const float*)d_in[2];
  const float* bq   = (const float*)d_in[3];
  const float* Wkv  = (const float*)d_in[4];
  const float* bkv  = (const float*)d_in[5];
  const float* Wo   = (const float*)d_in[6];
  const float* bo   = (const float*)d_in[7];
  const float* gamma = (const float*)d_in[8];
  const float* beta  = (const float*)d_in[9];
  float* out = (float*)d_out;

  char* ws = (char*)d_ws;
  unsigned short* Xb   = (unsigned short*)(ws + (size_t)0);
  unsigned short* Cb   = (unsigned short*)(ws + ((size_t)8  << 20));
  unsigned short* Qb   = (unsigned short*)(ws + ((size_t)16 << 20));
  unsigned short* KVb  = (unsigned short*)(ws + ((size_t)24 << 20));
  unsigned short* Abuf = (unsigned short*)(ws + ((size_t)40 << 20));
  // Vt aliases tmpb's region: written by projmm, consumed by attn, dead
  // before k_omm writes tmpb (stream-serialized).
  unsigned short* Vt   = (unsigned short*)(ws + ((size_t)48 << 20));
  unsigned short* tmpb = (unsigned short*)(ws + ((size_t)48 << 20));
  unsigned short* Wqt  = (unsigned short*)(ws + ((size_t)64 << 20));
  unsigned short* Wkvt = (unsigned short*)(ws + ((size_t)65 << 20));
  unsigned short* Wot  = (unsigned short*)(ws + ((size_t)67 << 20));

  // preprocessing: both casts + all 3 weight transposes
  k_pre<<<8448, 256, 0, stream>>>(layer_input, Xb, cross, Cb,
                                  Wq, Wqt, Wkv, Wkvt, Wo, Wot);
  // merged Q + KV projections (Q pre-scaled by 0.125*log2e; V transposed)
  k_projmm<<<1536, 256, 0, stream>>>(Xb, Cb, Wqt, Wkvt, bq, bkv, Qb, KVb, Vt);
  // attention (512 blocks of 128 q-rows, XCD-swizzled; 32 q-rows/wave)
  k_attn<<<512, 256, 0, stream>>>(Qb, KVb, Vt, Abuf);
  // output projection + bias + bf16 residual -> bf16 tmp
  k_omm<<<512, 256, 0, stream>>>(Abuf, Wot, bo, Xb, tmpb);
  // layernorm (bf16 in, f32 out)
  k_ln<<<MTOT/4, 256, 0, stream>>>(tmpb, gamma, beta, out);
}